// Round 4
// baseline (286.594 us; speedup 1.0000x reference)
//
#include <hip/hip_runtime.h>
#include <hip/hip_bf16.h>
#include <stdint.h>
#include <math.h>

typedef __bf16 bf16;
typedef __bf16 bf16x4 __attribute__((ext_vector_type(4)));
typedef __bf16 bf16x8 __attribute__((ext_vector_type(8)));
typedef float f32x4 __attribute__((ext_vector_type(4)));

// Problem constants
#define BB 4
#define TT 2048
#define CC 1024
#define HH 16
#define DK 64

// async global->LDS, 16B per lane. LDS dest = wave-uniform base + lane*16.
__device__ __forceinline__ void gl_lds16(const void* gsrc, void* ldst) {
    __builtin_amdgcn_global_load_lds(
        (__attribute__((address_space(1))) void*)(void*)(gsrc),
        (__attribute__((address_space(3))) void*)(ldst),
        16, 0, 0);
}

// ---- m201-faithful sync layer ----
// NO memory clobbers (they force compiler vmcnt drains - round 1).
// NO asm ds_reads (volatile asm serializes reads against MFMA - rounds 2-3).
// Plain C++ LDS reads + raw barrier + clean counted waits = the m201 cell.
__device__ __forceinline__ void bar() { __builtin_amdgcn_s_barrier(); }
#define VMCNT(N) asm volatile("s_waitcnt vmcnt(" #N ")")
#define LGKM0() asm volatile("s_waitcnt lgkmcnt(0)")

// ---------------------------------------------------------------------------
// prep: x->bf16 convert + both weight transposes (one kernel, 8192 blocks).
// ---------------------------------------------------------------------------
__global__ __launch_bounds__(256) void prep(
    const float* __restrict__ x, const float* __restrict__ wq,
    const float* __restrict__ wo, bf16* __restrict__ xbf,
    bf16* __restrict__ wqT, bf16* __restrict__ woT) {
    __shared__ bf16 tile[32][33];
    const int bid = blockIdx.x, tid = threadIdx.x;
    if (bid < 4096) {
        const int i = (bid * 256 + tid) * 8;
        const f32x4 a = *(const f32x4*)(x + i);
        const f32x4 b = *(const f32x4*)(x + i + 4);
        bf16x8 o;
#pragma unroll
        for (int j = 0; j < 4; ++j) { o[j] = (bf16)a[j]; o[j + 4] = (bf16)b[j]; }
        *(bf16x8*)(xbf + i) = o;
        return;
    }
    const float* in;
    bf16* out;
    int R, C, c0, r0;
    if (bid < 7168) {
        const int tb = bid - 4096;       // 96 x 32 tiles
        in = wq; out = wqT; R = 1024; C = 3072;
        c0 = (tb % 96) * 32; r0 = (tb / 96) * 32;
    } else {
        const int tb = bid - 7168;       // 32 x 32 tiles
        in = wo; out = woT; R = 1024; C = 1024;
        c0 = (tb % 32) * 32; r0 = (tb / 32) * 32;
    }
    const int tx = tid & 31, ty = tid >> 5;
#pragma unroll
    for (int i = 0; i < 32; i += 8)
        tile[ty + i][tx] = (bf16)in[(size_t)(r0 + ty + i) * C + c0 + tx];
    __syncthreads();
#pragma unroll
    for (int i = 0; i < 32; i += 8)
        out[(size_t)(c0 + ty + i) * R + r0 + tx] = tile[tx][ty + i];
}

// ---------------------------------------------------------------------------
// GEMM v5: m201-faithful phase bodies. 256x256, BK=64, 8 waves (2Mx4N).
// Per K-tile t (buffer cur=t&1), 4 phases; each phase:
//   { plain ds-reads of this phase's frags; stage 1 half-tile;
//     bar; lgkmcnt(0); setprio(1); 16 MFMA; setprio(0); [vmcnt]; bar }
// Quadrants: P0 AExBE, P1 AExBL, P2 ALxBL, P3 ALxBE (be/bl regs held).
// Ledger (instr units, 2 per half-tile stage; round-1-verified):
//   steady: P0 stages BE'(t+1), P1 BL'(t+1), P2 AL'(t+1), P3 AE''(t+2)->cur.
//   end-P1 VMCNT(6): drains AL'(t) needed by P2 reads.
//   end-P3 VMCNT(4): drains BE',BL' (and older) needed by next P0/P1.
//   AE''->cur write-safe: cur A-early reads lgkm-complete before end-P1 bar,
//   AE'' issues at P3 (after end-P2 bar).
// Tail: t=NT-2 end-P3 VMCNT(2); t=NT-1 end-P1 VMCNT(0), no stages.
// ---------------------------------------------------------------------------
template <int EPI>
__global__ __launch_bounds__(512, 2) void gemm256(
    const bf16* __restrict__ A, const bf16* __restrict__ Bt,
    void* __restrict__ Cq, bf16* __restrict__ Kh, bf16* __restrict__ Vt,
    int M, int N, int K, int nxg) {
    __shared__ bf16 As[2][256 * 64];   // 2 x 32 KiB
    __shared__ bf16 Bs[2][256 * 64];   // 2 x 32 KiB
    const int tid = threadIdx.x;
    const int w = tid >> 6, l = tid & 63;
    const int wm = w >> 2, wn = w & 3;          // wave grid 2 x 4
    const int lm = l & 15, lq = l >> 4;

    // XCD-aware swizzle (gridDim.x % 8 == 0 for both call sites)
    const int nwg = gridDim.x;
    const int sw = (blockIdx.x & 7) * (nwg >> 3) + (blockIdx.x >> 3);
    const int bx = sw % nxg, by = sw / nxg;
    const int m0 = by * 256, n0 = bx * 256;

    // ---- staging geometry (global source pre-swizzled: slot ^= row&7) ----
    const int srow_a = w * 8 + (l >> 3);                       // A: 64 rows/call
    const int srow_b = (w & 3) * 8 + (w >> 2) * 64 + (l >> 3); // B: 2x32-row stripes
    const int csw = ((l & 7) ^ (l >> 3)) * 8;                  // swizzled col (elems)
    const bf16* agl = A + (size_t)(m0 + srow_a) * K + csw;
    const bf16* bgl = Bt + (size_t)(n0 + srow_b) * K + csw;
    const int wa = w * 8;
    const int wb = (w & 3) * 8 + (w >> 2) * 64;

    // ---- swizzled LDS read offsets (elements); row&7 == lm&7 for frags ----
    int aoffE[2], boffE[2];
#pragma unroll
    for (int ks = 0; ks < 2; ++ks) {
        const int sl = (ks * 4 + lq) ^ (lm & 7);
        aoffE[ks] = (wm * 128 + lm) * 64 + sl * 8;
        boffE[ks] = (wn * 64 + lm) * 64 + sl * 8;
    }

    f32x4 acc[8][4] = {};
    bf16x8 af[4][2], be[2][2], bl[2][2];

#define STGA(R, DSTA, KOFF) gl_lds16(agl + (size_t)(R) * K + (KOFF), (DSTA) + (wa + (R)) * 64)
#define STGB(R, DSTB, KOFF) gl_lds16(bgl + (size_t)(R) * K + (KOFF), (DSTB) + (wb + (R)) * 64)
#define QMFMA(MIH, NIH, BF)                                                    \
    __builtin_amdgcn_s_setprio(1);                                             \
    _Pragma("unroll") for (int ks = 0; ks < 2; ++ks)                           \
    _Pragma("unroll") for (int mi = 0; mi < 4; ++mi)                           \
    _Pragma("unroll") for (int ni = 0; ni < 2; ++ni)                           \
        acc[(MIH) * 4 + mi][(NIH) * 2 + ni] =                                  \
            __builtin_amdgcn_mfma_f32_16x16x32_bf16(                           \
                af[mi][ks], BF[ni][ks], acc[(MIH) * 4 + mi][(NIH) * 2 + ni],   \
                0, 0, 0);                                                      \
    __builtin_amdgcn_s_setprio(0);

    bf16* A0 = &As[0][0]; bf16* A1 = &As[1][0];
    bf16* B0 = &Bs[0][0]; bf16* B1 = &Bs[1][0];
    const int NT = K >> 6;   // assumed >= 3 (K = 1024 here)

    // prologue: tile0 {AE,BE,BL,AL} -> buf0, AE(1) -> buf1.
    STGA(0, A0, 0); STGA(128, A0, 0);     // AE0
    STGB(0, B0, 0); STGB(128, B0, 0);     // BE0
    STGB(32, B0, 0); STGB(160, B0, 0);    // BL0
    STGA(64, A0, 0); STGA(192, A0, 0);    // AL0
    STGA(0, A1, 64); STGA(128, A1, 64);   // AE1
    VMCNT(4); bar();                      // AE0,BE0,BL0 landed; AL0,AE1 in flight

    for (int t = 0; t < NT; ++t) {
        const int bb = t & 1;
        const bf16* Ac = bb ? A1 : A0;  const bf16* Bc = bb ? B1 : B0;
        bf16* An = bb ? A0 : A1;        bf16* Bn = bb ? B0 : B1;  // tile t+1
        bf16* Aw = bb ? A1 : A0;                                  // tile t+2 (cur)
        const int k1 = (t + 1) << 6, k2 = (t + 2) << 6;
        const bool sN = (t + 1 < NT), sN2 = (t + 2 < NT);

        // ---------------- P0: AE x BE ----------------
#pragma unroll
        for (int mi = 0; mi < 4; ++mi)
#pragma unroll
            for (int ks = 0; ks < 2; ++ks)
                af[mi][ks] = *(const bf16x8*)(Ac + aoffE[ks] + mi * 1024);
#pragma unroll
        for (int ni = 0; ni < 2; ++ni)
#pragma unroll
            for (int ks = 0; ks < 2; ++ks)
                be[ni][ks] = *(const bf16x8*)(Bc + boffE[ks] + ni * 1024);
        if (sN) { STGB(0, Bn, k1); STGB(128, Bn, k1); }      // BE'
        bar();
        LGKM0();
        QMFMA(0, 0, be);
        bar();
        // ---------------- P1: AE x BL ----------------
#pragma unroll
        for (int ni = 0; ni < 2; ++ni)
#pragma unroll
            for (int ks = 0; ks < 2; ++ks)
                bl[ni][ks] = *(const bf16x8*)(Bc + boffE[ks] + (2 + ni) * 1024);
        if (sN) { STGB(32, Bn, k1); STGB(160, Bn, k1); }     // BL'
        bar();
        LGKM0();
        QMFMA(0, 1, bl);
        if (sN) { VMCNT(6); } else { VMCNT(0); }             // drain AL'(t)
        bar();
        // ---------------- P2: AL x BL ----------------
#pragma unroll
        for (int mi = 0; mi < 4; ++mi)
#pragma unroll
            for (int ks = 0; ks < 2; ++ks)
                af[mi][ks] = *(const bf16x8*)(Ac + aoffE[ks] + 4096 + mi * 1024);
        if (sN) { STGA(64, An, k1); STGA(192, An, k1); }     // AL'
        bar();
        LGKM0();
        QMFMA(1, 1, bl);
        bar();
        // ---------------- P3: AL x BE ----------------
        if (sN2) { STGA(0, Aw, k2); STGA(128, Aw, k2); }     // AE'' -> cur buf
        bar();
        QMFMA(1, 0, be);
        if (sN2) { VMCNT(4); }                               // drain BE',BL'
        else if (sN) { VMCNT(2); }
        bar();
    }

    if (EPI == 0) {
#pragma unroll
        for (int mi = 0; mi < 8; ++mi) {
            const int row = m0 + wm * 128 + mi * 16 + lq * 4;
#pragma unroll
            for (int ni = 0; ni < 4; ++ni) {
                const int col = n0 + wn * 64 + ni * 16 + lm;
#pragma unroll
                for (int r = 0; r < 4; ++r)
                    ((float*)Cq)[(size_t)(row + r) * N + col] = acc[mi][ni][r];
            }
        }
    } else {
        bf16* Q = (bf16*)Cq;
#pragma unroll
        for (int ni = 0; ni < 4; ++ni) {
            const int c = n0 + wn * 64 + ni * 16 + lm;
            const int part = c >> 10;
            const int h = (c & 1023) >> 6;
            const int d = c & 63;
#pragma unroll
            for (int mi = 0; mi < 8; ++mi) {
                const int rowg = m0 + wm * 128 + mi * 16 + lq * 4;
#pragma unroll
                for (int r = 0; r < 4; ++r) {
                    const int rg = rowg + r;
                    const int b = rg >> 11, t = rg & 2047;
                    const bf16 v = (bf16)acc[mi][ni][r];
                    if (part == 0)
                        Q[((size_t)(b * HH + h) * TT + t) * DK + d] = v;
                    else if (part == 1)
                        Kh[((size_t)(b * HH + h) * TT + t) * DK + d] = v;
                    else
                        Vt[((size_t)(b * HH + h) * DK + d) * TT + t] = v;
                }
            }
        }
    }
#undef STGA
#undef STGB
#undef QMFMA
}

// ---------------------------------------------------------------------------
// Causal flash attention, v5 (unchanged this round).
// ---------------------------------------------------------------------------
#define PAD 72
__global__ __launch_bounds__(256, 3) void attn_kernel(
    const bf16* __restrict__ Qh, const bf16* __restrict__ Kh,
    const bf16* __restrict__ Vt, bf16* __restrict__ O) {
    __shared__ bf16 Ks[2][64 * PAD];
    __shared__ bf16 Vs[2][64 * PAD];
    __shared__ bf16 Ps[64 * PAD];
    const int tid = threadIdx.x, w = tid >> 6, l = tid & 63;
    const int lm = l & 15, lq = l >> 4;
    const int id = blockIdx.x;                 // 0..1023
    const int xcd = id & 7;
    const int rest = id >> 3;                  // 0..127
    const int bh = xcd + 8 * (rest >> 4);      // 0..63 (8 heads per XCD)
    const int p = rest & 15;                   // 0..15 (q-tile pair)
    const int b = bh >> 4, h = bh & 15;
    const bf16* Qb = Qh + (size_t)bh * TT * DK;
    const bf16* Kb = Kh + (size_t)bh * TT * DK;
    const bf16* Vb = Vt + (size_t)bh * DK * TT;
    const int srow = tid >> 3, scol = (tid & 7) * 8;  // staging: 32 rows x 64 cols

    const float smul = 0.125f * 1.44269504088896340736f;  // scale * log2(e)
    const int qts[2] = {p, 31 - p};

    // prologue: load first K/V tile (qts[0], kt=0) into regs
    bf16x8 kreg[2], vreg[2];
#pragma unroll
    for (int i = 0; i < 2; ++i) {
        kreg[i] = *(const bf16x8*)(Kb + (size_t)(srow + i * 32) * DK + scol);
        vreg[i] = *(const bf16x8*)(Vb + (size_t)(srow + i * 32) * TT + scol);
    }
    int buf = 0;

#pragma unroll
    for (int half = 0; half < 2; ++half) {
        const int qt = qts[half];
        const int q0 = qt * 64;
        const int qg = q0 + w * 16 + lm;  // this lane's q row (softmax view)

        // Q fragments straight from global
        bf16x8 qf[2];
#pragma unroll
        for (int ks = 0; ks < 2; ++ks)
            qf[ks] = *(const bf16x8*)(Qb + (size_t)(q0 + w * 16 + lm) * DK +
                                      ks * 32 + lq * 8);

        f32x4 oacc[4] = {};
        float lrun = 0.f;

        for (int kt = 0; kt <= qt; ++kt) {
            // commit staged regs to LDS buffer
#pragma unroll
            for (int i = 0; i < 2; ++i) {
                *(bf16x8*)(Ks[buf] + (srow + i * 32) * PAD + scol) = kreg[i];
                *(bf16x8*)(Vs[buf] + (srow + i * 32) * PAD + scol) = vreg[i];
            }
            __syncthreads();

            // prefetch next tile (next kt, or first tile of next half)
            {
                int nkt = -1;
                if (kt < qt) nkt = kt + 1;
                else if (half == 0) nkt = 0;
                if (nkt >= 0) {
#pragma unroll
                    for (int i = 0; i < 2; ++i) {
                        kreg[i] = *(const bf16x8*)(
                            Kb + (size_t)(nkt * 64 + srow + i * 32) * DK + scol);
                        vreg[i] = *(const bf16x8*)(
                            Vb + (size_t)(srow + i * 32) * TT + nkt * 64 + scol);
                    }
                }
            }

            // S^T = K @ Q^T
            f32x4 st[4] = {};
#pragma unroll
            for (int ks = 0; ks < 2; ++ks) {
#pragma unroll
                for (int nb = 0; nb < 4; ++nb) {
                    const bf16x8 kf = *(const bf16x8*)(Ks[buf] + (nb * 16 + lm) * PAD +
                                                       ks * 32 + lq * 8);
                    st[nb] = __builtin_amdgcn_mfma_f32_16x16x32_bf16(
                        kf, qf[ks], st[nb], 0, 0, 0);
                }
            }

            // fixed-shift softmax: p = exp2(s*smul - 20)
            const bool diag = (kt == qt);
#pragma unroll
            for (int nb = 0; nb < 4; ++nb) {
                bf16x4 pk;
#pragma unroll
                for (int r = 0; r < 4; ++r) {
                    float arg = fmaf(st[nb][r], smul, -20.f);
                    if (diag) {
                        const int keyg = kt * 64 + nb * 16 + lq * 4 + r;
                        if (keyg > qg) arg = -1e30f;
                    }
                    const float pv = exp2f(arg);
                    lrun += pv;
                    pk[r] = (bf16)pv;
                }
                *(bf16x4*)(Ps + (w * 16 + lm) * PAD + nb * 16 + lq * 4) = pk;
            }
            // no barrier: P rows of wave w are written and read only by wave w

            // O += P @ V
#pragma unroll
            for (int ks = 0; ks < 2; ++ks) {
                const bf16x8 pf =
                    *(const bf16x8*)(Ps + (w * 16 + lm) * PAD + ks * 32 + lq * 8);
#pragma unroll
                for (int ni = 0; ni < 4; ++ni) {
                    const bf16x8 vf = *(const bf16x8*)(Vs[buf] + (ni * 16 + lm) * PAD +
                                                       ks * 32 + lq * 8);
                    oacc[ni] = __builtin_amdgcn_mfma_f32_16x16x32_bf16(
                        pf, vf, oacc[ni], 0, 0, 0);
                }
            }
            buf ^= 1;
            // no trailing barrier: next iter writes the other buffer
        }

        // epilogue (barrier-free): reduce l across lq partners, bcast via shfl
        lrun += __shfl_xor(lrun, 16);
        lrun += __shfl_xor(lrun, 32);
        float linv[4];
#pragma unroll
        for (int r = 0; r < 4; ++r) linv[r] = 1.0f / __shfl(lrun, lq * 4 + r);
#pragma unroll
        for (int ni = 0; ni < 4; ++ni) {
            const int col = h * 64 + ni * 16 + lm;
#pragma unroll
            for (int r = 0; r < 4; ++r) {
                const int t = q0 + w * 16 + lq * 4 + r;
                O[((size_t)(b * TT + t)) * CC + col] = (bf16)(oacc[ni][r] * linv[r]);
            }
        }
    }
}

// ---------------------------------------------------------------------------
extern "C" void kernel_launch(void* const* d_in, const int* in_sizes, int n_in,
                              void* d_out, int out_size, void* d_ws, size_t ws_size,
                              hipStream_t stream) {
    const float* x = (const float*)d_in[0];       // (8192, 1024) f32
    const float* w_qkv = (const float*)d_in[1];   // (1024, 3072) f32
    const float* w_out = (const float*)d_in[2];   // (1024, 1024) f32

    char* ws = (char*)d_ws;
    const size_t M1 = (size_t)1 << 20;
    bf16* Qh = (bf16*)(ws);                  // (B,H,T,64)   16 MiB
    bf16* Kh = (bf16*)(ws + 16 * M1);        // (B,H,T,64)   16 MiB
    bf16* Vt = (bf16*)(ws + 32 * M1);        // (B,H,64,T)   16 MiB
    bf16* Ob = (bf16*)(ws + 48 * M1);        // (8192,1024)  16 MiB
    bf16* wqkvT = (bf16*)(ws + 64 * M1);     // (3072,1024)   6 MiB
    bf16* woutT = (bf16*)(ws + 70 * M1);     // (1024,1024)   2 MiB
    bf16* xbf = (bf16*)(ws + 72 * M1);       // (8192,1024)  16 MiB

    prep<<<8192, 256, 0, stream>>>(x, w_qkv, w_out, xbf, wqkvT, woutT);
    gemm256<1><<<384, 512, 0, stream>>>(
        xbf, wqkvT, Qh, Kh, Vt, 8192, 3072, 1024, 12);
    attn_kernel<<<1024, 256, 0, stream>>>(Qh, Kh, Vt, Ob);
    gemm256<0><<<128, 512, 0, stream>>>(
        Ob, woutT, (float*)d_out, nullptr, nullptr, 8192, 1024, 1024, 4);
}

// Round 6
// 274.307 us; speedup vs baseline: 1.0448x; 1.0448x over previous
//
#include <hip/hip_runtime.h>
#include <hip/hip_bf16.h>
#include <stdint.h>
#include <math.h>

typedef __bf16 bf16;
typedef __bf16 bf16x4 __attribute__((ext_vector_type(4)));
typedef __bf16 bf16x8 __attribute__((ext_vector_type(8)));
typedef float f32x4 __attribute__((ext_vector_type(4)));

// Problem constants
#define BB 4
#define TT 2048
#define CC 1024
#define HH 16
#define DK 64

// async global->LDS, 16B per lane. LDS dest = wave-uniform base + lane*16.
__device__ __forceinline__ void gl_lds16(const void* gsrc, void* ldst) {
    __builtin_amdgcn_global_load_lds(
        (__attribute__((address_space(1))) void*)(void*)(gsrc),
        (__attribute__((address_space(3))) void*)(ldst),
        16, 0, 0);
}

// sync layer used by gemm256 (round-1 measured variant, 96.9us)
__device__ __forceinline__ void bar() {
    asm volatile("" ::: "memory");
    __builtin_amdgcn_s_barrier();
    asm volatile("" ::: "memory");
}
#define VMCNT(N) asm volatile("s_waitcnt vmcnt(" #N ")" ::: "memory")

// ---------------------------------------------------------------------------
// prep: x->bf16 convert + both weight transposes (one kernel, 8192 blocks).
// ---------------------------------------------------------------------------
__global__ __launch_bounds__(256) void prep(
    const float* __restrict__ x, const float* __restrict__ wq,
    const float* __restrict__ wo, bf16* __restrict__ xbf,
    bf16* __restrict__ wqT, bf16* __restrict__ woT) {
    __shared__ bf16 tile[32][33];
    const int bid = blockIdx.x, tid = threadIdx.x;
    if (bid < 4096) {
        const int i = (bid * 256 + tid) * 8;
        const f32x4 a = *(const f32x4*)(x + i);
        const f32x4 b = *(const f32x4*)(x + i + 4);
        bf16x8 o;
#pragma unroll
        for (int j = 0; j < 4; ++j) { o[j] = (bf16)a[j]; o[j + 4] = (bf16)b[j]; }
        *(bf16x8*)(xbf + i) = o;
        return;
    }
    const float* in;
    bf16* out;
    int R, C, c0, r0;
    if (bid < 7168) {
        const int tb = bid - 4096;       // 96 x 32 tiles
        in = wq; out = wqT; R = 1024; C = 3072;
        c0 = (tb % 96) * 32; r0 = (tb / 96) * 32;
    } else {
        const int tb = bid - 7168;       // 32 x 32 tiles
        in = wo; out = woT; R = 1024; C = 1024;
        c0 = (tb % 32) * 32; r0 = (tb / 32) * 32;
    }
    const int tx = tid & 31, ty = tid >> 5;
#pragma unroll
    for (int i = 0; i < 32; i += 8)
        tile[ty + i][tx] = (bf16)in[(size_t)(r0 + ty + i) * C + c0 + tx];
    __syncthreads();
#pragma unroll
    for (int i = 0; i < 32; i += 8)
        out[(size_t)(c0 + ty + i) * R + r0 + tx] = tile[tx][ty + i];
}

// ---------------------------------------------------------------------------
// gemm256: ROUND-1 VERBATIM (measured 96.9us on QKV). 256x256, BK=64,
// 8 waves. Used only for the QKV GEMM (EPI=1).
// ---------------------------------------------------------------------------
template <int EPI>
__global__ __launch_bounds__(512, 2) void gemm256(
    const bf16* __restrict__ A, const bf16* __restrict__ Bt,
    void* __restrict__ Cq, bf16* __restrict__ Kh, bf16* __restrict__ Vt,
    int M, int N, int K) {
    __shared__ bf16 As[2][256 * 64];   // 2 x 32 KiB
    __shared__ bf16 Bs[2][256 * 64];   // 2 x 32 KiB
    const int tid = threadIdx.x;
    const int w = tid >> 6, l = tid & 63;
    const int wm = w >> 2, wn = w & 3;          // wave grid 2 x 4
    const int lm = l & 15, lq = l >> 4;
    const int m0 = blockIdx.y * 256, n0 = blockIdx.x * 256;

    // ---- staging geometry (global source pre-swizzled: slot ^= row&7) ----
    const int srow_a = w * 8 + (l >> 3);                       // A: 64 contig rows/call
    const int srow_b = (w & 3) * 8 + (w >> 2) * 64 + (l >> 3); // B: 2x32-row stripes/call
    const int csw = ((l & 7) ^ (l >> 3)) * 8;                  // swizzled col (elems)
    const bf16* agl = A + (size_t)(m0 + srow_a) * K + csw;
    const bf16* bgl = Bt + (size_t)(n0 + srow_b) * K + csw;
    const int wa = w * 8;
    const int wb = (w & 3) * 8 + (w >> 2) * 64;

    // ---- swizzled LDS read offsets (elements); row&7 == lm&7 for frags ----
    int aoff[2], boff[2];
#pragma unroll
    for (int ks = 0; ks < 2; ++ks) {
        const int sl = (ks * 4 + lq) ^ (lm & 7);
        aoff[ks] = (wm * 128 + lm) * 64 + sl * 8;
        boff[ks] = (wn * 64 + lm) * 64 + sl * 8;
    }

    f32x4 acc[8][4] = {};
    bf16x8 af[4][2], bfA[2][2], bfB[2][2];

#define STGA(R, DSTA, KOFF) gl_lds16(agl + (size_t)(R) * K + (KOFF), (DSTA) + (wa + (R)) * 64)
#define STGB(R, DSTB, KOFF) gl_lds16(bgl + (size_t)(R) * K + (KOFF), (DSTB) + (wb + (R)) * 64)
#define LDA(MIH, SRC)                                                          \
    _Pragma("unroll") for (int mi = 0; mi < 4; ++mi)                           \
    _Pragma("unroll") for (int ks = 0; ks < 2; ++ks)                           \
        af[mi][ks] = *(const bf16x8*)((SRC) + aoff[ks] + ((MIH) * 4 + mi) * 1024);
#define LDB(BF, NIH, SRC)                                                      \
    _Pragma("unroll") for (int ni = 0; ni < 2; ++ni)                           \
    _Pragma("unroll") for (int ks = 0; ks < 2; ++ks)                           \
        BF[ni][ks] = *(const bf16x8*)((SRC) + boff[ks] + ((NIH) * 2 + ni) * 1024);
#define QMFMA(MIH, NIH, BF)                                                    \
    __builtin_amdgcn_s_setprio(1);                                             \
    _Pragma("unroll") for (int ks = 0; ks < 2; ++ks)                           \
    _Pragma("unroll") for (int mi = 0; mi < 4; ++mi)                           \
    _Pragma("unroll") for (int ni = 0; ni < 2; ++ni)                           \
        acc[(MIH) * 4 + mi][(NIH) * 2 + ni] =                                  \
            __builtin_amdgcn_mfma_f32_16x16x32_bf16(                           \
                af[mi][ks], BF[ni][ks], acc[(MIH) * 4 + mi][(NIH) * 2 + ni],   \
                0, 0, 0);                                                      \
    __builtin_amdgcn_s_setprio(0);

    bf16* A0 = &As[0][0]; bf16* A1 = &As[1][0];
    bf16* B0 = &Bs[0][0]; bf16* B1 = &Bs[1][0];
    const int NT = K >> 6;

    // prologue: tile 0 -> buffer 0, order AE,BE,BL,AL; AE/BE must land now.
    STGA(0, A0, 0); STGA(128, A0, 0);
    STGB(0, B0, 0); STGB(128, B0, 0);
    STGB(32, B0, 0); STGB(160, B0, 0);
    STGA(64, A0, 0); STGA(192, A0, 0);
    VMCNT(4); bar();

    for (int t = 0; t < NT - 1; ++t) {
        const int bb = t & 1;
        const bf16* Ac = bb ? A1 : A0; const bf16* Bc = bb ? B1 : B0;
        bf16* An = bb ? A0 : A1;       bf16* Bn = bb ? B0 : B1;
        const int k1 = (t + 1) << 6;
        // P0: quadrant (mi0-3, ni0-1)
        LDA(0, Ac); LDB(bfA, 0, Bc);
        STGA(0, An, k1); STGA(128, An, k1);        // AE'
        bar();
        QMFMA(0, 0, bfA);
        VMCNT(4); bar();
        // P1: quadrant (mi0-3, ni2-3)
        LDB(bfB, 1, Bc);
        STGB(0, Bn, k1); STGB(128, Bn, k1);        // BE'
        bar();
        QMFMA(0, 1, bfB);
        VMCNT(4); bar();
        // P2: quadrant (mi4-7, ni2-3)
        LDA(1, Ac);
        STGB(32, Bn, k1); STGB(160, Bn, k1);       // BL'
        bar();
        QMFMA(1, 1, bfB);
        bar();
        // P3: quadrant (mi4-7, ni0-1)
        STGA(64, An, k1); STGA(192, An, k1);       // AL'
        bar();
        QMFMA(1, 0, bfA);
        VMCNT(4); bar();
    }
    {   // last tile: drain 4 -> 2 -> 0
        const int bb = (NT - 1) & 1;
        const bf16* Ac = bb ? A1 : A0; const bf16* Bc = bb ? B1 : B0;
        LDA(0, Ac); LDB(bfA, 0, Bc);
        bar(); QMFMA(0, 0, bfA); VMCNT(2); bar();
        LDB(bfB, 1, Bc);
        bar(); QMFMA(0, 1, bfB); VMCNT(0); bar();
        LDA(1, Ac);
        bar(); QMFMA(1, 1, bfB); bar();
        QMFMA(1, 0, bfA);
    }

    if (EPI == 0) {
#pragma unroll
        for (int mi = 0; mi < 8; ++mi) {
            const int row = m0 + wm * 128 + mi * 16 + lq * 4;
#pragma unroll
            for (int ni = 0; ni < 4; ++ni) {
                const int col = n0 + wn * 64 + ni * 16 + lm;
#pragma unroll
                for (int r = 0; r < 4; ++r)
                    ((float*)Cq)[(size_t)(row + r) * N + col] = acc[mi][ni][r];
            }
        }
    } else {
        bf16* Q = (bf16*)Cq;
#pragma unroll
        for (int ni = 0; ni < 4; ++ni) {
            const int c = n0 + wn * 64 + ni * 16 + lm;
            const int part = c >> 10;
            const int h = (c & 1023) >> 6;
            const int d = c & 63;
#pragma unroll
            for (int mi = 0; mi < 8; ++mi) {
                const int rowg = m0 + wm * 128 + mi * 16 + lq * 4;
#pragma unroll
                for (int r = 0; r < 4; ++r) {
                    const int rg = rowg + r;
                    const int b = rg >> 11, t = rg & 2047;
                    const bf16 v = (bf16)acc[mi][ni][r];
                    if (part == 0)
                        Q[((size_t)(b * HH + h) * TT + t) * DK + d] = v;
                    else if (part == 1)
                        Kh[((size_t)(b * HH + h) * TT + t) * DK + d] = v;
                    else
                        Vt[((size_t)(b * HH + h) * DK + d) * TT + t] = v;
                }
            }
        }
    }
#undef STGA
#undef STGB
#undef LDA
#undef LDB
#undef QMFMA
}

// ---------------------------------------------------------------------------
// gemm_bt: ROUND-0 VERBATIM 128x128 m97 structure (measured ~34us on the
// 1024-wide projection: 512 blocks, 3 blocks/CU, good balance).
// ---------------------------------------------------------------------------
template <int EPI>
__global__ __launch_bounds__(256) void gemm_bt(
    const bf16* __restrict__ A, const bf16* __restrict__ Bt,
    void* __restrict__ Cq, bf16* __restrict__ Kh, bf16* __restrict__ Vt,
    int M, int N, int K) {
    __shared__ bf16 As[128 * 32];
    __shared__ bf16 Bs[128 * 32];
    const int tid = threadIdx.x;
    const int w = tid >> 6, l = tid & 63;
    const int wm = w >> 1, wn = w & 1;
    const int m0 = blockIdx.y * 128, n0 = blockIdx.x * 128;
    const int lr4 = l >> 2, lc4 = (l & 3) * 8;
    const int lm = l & 15, lq = l >> 4;

    f32x4 acc[4][4] = {};

    for (int k0 = 0; k0 < K; k0 += 32) {
#pragma unroll
        for (int i = 0; i < 2; ++i) {
            const int j = w * 2 + i;
            gl_lds16(A + (size_t)(m0 + j * 16 + lr4) * K + k0 + lc4, As + j * 512);
            gl_lds16(Bt + (size_t)(n0 + j * 16 + lr4) * K + k0 + lc4, Bs + j * 512);
        }
        __syncthreads();
        bf16x8 af[4], bfr[4];
#pragma unroll
        for (int mi = 0; mi < 4; ++mi)
            af[mi] = *(const bf16x8*)(As + (wm * 64 + mi * 16 + lm) * 32 + lq * 8);
#pragma unroll
        for (int ni = 0; ni < 4; ++ni)
            bfr[ni] = *(const bf16x8*)(Bs + (wn * 64 + ni * 16 + lm) * 32 + lq * 8);
#pragma unroll
        for (int mi = 0; mi < 4; ++mi)
#pragma unroll
            for (int ni = 0; ni < 4; ++ni)
                acc[mi][ni] = __builtin_amdgcn_mfma_f32_16x16x32_bf16(
                    af[mi], bfr[ni], acc[mi][ni], 0, 0, 0);
        __syncthreads();
    }

    if (EPI == 0) {
#pragma unroll
        for (int mi = 0; mi < 4; ++mi) {
            const int row = m0 + wm * 64 + mi * 16 + lq * 4;
#pragma unroll
            for (int ni = 0; ni < 4; ++ni) {
                const int col = n0 + wn * 64 + ni * 16 + lm;
#pragma unroll
                for (int r = 0; r < 4; ++r)
                    ((float*)Cq)[(size_t)(row + r) * N + col] = acc[mi][ni][r];
            }
        }
    } else {
        bf16* Q = (bf16*)Cq;
#pragma unroll
        for (int ni = 0; ni < 4; ++ni) {
            const int c = n0 + wn * 64 + ni * 16 + lm;
            const int part = c >> 10;
            const int h = (c & 1023) >> 6;
            const int d = c & 63;
#pragma unroll
            for (int mi = 0; mi < 4; ++mi) {
                const int rowg = m0 + wm * 64 + mi * 16 + lq * 4;
#pragma unroll
                for (int r = 0; r < 4; ++r) {
                    const int rg = rowg + r;
                    const int b = rg >> 11, t = rg & 2047;
                    const bf16 v = (bf16)acc[mi][ni][r];
                    if (part == 0)
                        Q[((size_t)(b * HH + h) * TT + t) * DK + d] = v;
                    else if (part == 1)
                        Kh[((size_t)(b * HH + h) * TT + t) * DK + d] = v;
                    else
                        Vt[((size_t)(b * HH + h) * DK + d) * TT + t] = v;
                }
            }
        }
    }
}

// ---------------------------------------------------------------------------
// Causal flash attention, v6 (resubmit of round 5 — infra failure, never ran).
// v5 + occupancy push: the dedicated Ps buffer is DELETED — P lives in the
// dead K double-buffer half Ks[buf^1] (holds last iter's K tile, fully
// consumed before this iter's barrier). Race-freedom vs next iter's commit:
// each wave's P rows are remapped to exactly the rows that THE SAME wave
// commits (prow = 8w + (lm&7) + 32*(lm>>3)); per-wave DS ops are in-order,
// and different waves' row sets are disjoint. Any within-wave bijection
// lm->prow is correct since P is wave-private scratch.
// LDS 45->36 KB => 4 blocks/CU with __launch_bounds__(256,4); the 1024-block
// grid becomes exactly one full round (4 x 256). setprio around both MFMA
// clusters (T5, attn-positive per m191).
// ---------------------------------------------------------------------------
#define PAD 72
__global__ __launch_bounds__(256, 4) void attn_kernel(
    const bf16* __restrict__ Qh, const bf16* __restrict__ Kh,
    const bf16* __restrict__ Vt, bf16* __restrict__ O) {
    __shared__ bf16 Ks[2][64 * PAD];
    __shared__ bf16 Vs[2][64 * PAD];
    const int tid = threadIdx.x, w = tid >> 6, l = tid & 63;
    const int lm = l & 15, lq = l >> 4;
    const int id = blockIdx.x;                 // 0..1023
    const int xcd = id & 7;
    const int rest = id >> 3;                  // 0..127
    const int bh = xcd + 8 * (rest >> 4);      // 0..63 (8 heads per XCD)
    const int p = rest & 15;                   // 0..15 (q-tile pair)
    const int b = bh >> 4, h = bh & 15;
    const bf16* Qb = Qh + (size_t)bh * TT * DK;
    const bf16* Kb = Kh + (size_t)bh * TT * DK;
    const bf16* Vb = Vt + (size_t)bh * DK * TT;
    const int srow = tid >> 3, scol = (tid & 7) * 8;  // staging: 32 rows x 64 cols
    // P scratch row owned by this wave (matches this wave's commit rows)
    const int prow = w * 8 + (lm & 7) + ((lm >> 3) << 5);

    const float smul = 0.125f * 1.44269504088896340736f;  // scale * log2(e)
    const int qts[2] = {p, 31 - p};

    // prologue: load first K/V tile (qts[0], kt=0) into regs
    bf16x8 kreg[2], vreg[2];
#pragma unroll
    for (int i = 0; i < 2; ++i) {
        kreg[i] = *(const bf16x8*)(Kb + (size_t)(srow + i * 32) * DK + scol);
        vreg[i] = *(const bf16x8*)(Vb + (size_t)(srow + i * 32) * TT + scol);
    }
    int buf = 0;

#pragma unroll
    for (int half = 0; half < 2; ++half) {
        const int qt = qts[half];
        const int q0 = qt * 64;
        const int qg = q0 + w * 16 + lm;  // this lane's q row (softmax view)

        // Q fragments straight from global
        bf16x8 qf[2];
#pragma unroll
        for (int ks = 0; ks < 2; ++ks)
            qf[ks] = *(const bf16x8*)(Qb + (size_t)(q0 + w * 16 + lm) * DK +
                                      ks * 32 + lq * 8);

        f32x4 oacc[4] = {};
        float lrun = 0.f;

        for (int kt = 0; kt <= qt; ++kt) {
            // commit staged regs to LDS buffer
#pragma unroll
            for (int i = 0; i < 2; ++i) {
                *(bf16x8*)(Ks[buf] + (srow + i * 32) * PAD + scol) = kreg[i];
                *(bf16x8*)(Vs[buf] + (srow + i * 32) * PAD + scol) = vreg[i];
            }
            __syncthreads();

            // P scratch = dead K buffer half (this iter reads only Ks[buf])
            bf16* Pp = Ks[buf ^ 1];

            // prefetch next tile (next kt, or first tile of next half)
            {
                int nkt = -1;
                if (kt < qt) nkt = kt + 1;
                else if (half == 0) nkt = 0;
                if (nkt >= 0) {
#pragma unroll
                    for (int i = 0; i < 2; ++i) {
                        kreg[i] = *(const bf16x8*)(
                            Kb + (size_t)(nkt * 64 + srow + i * 32) * DK + scol);
                        vreg[i] = *(const bf16x8*)(
                            Vb + (size_t)(srow + i * 32) * TT + nkt * 64 + scol);
                    }
                }
            }

            // S^T = K @ Q^T
            f32x4 st[4] = {};
            __builtin_amdgcn_s_setprio(1);
#pragma unroll
            for (int ks = 0; ks < 2; ++ks) {
#pragma unroll
                for (int nb = 0; nb < 4; ++nb) {
                    const bf16x8 kf = *(const bf16x8*)(Ks[buf] + (nb * 16 + lm) * PAD +
                                                       ks * 32 + lq * 8);
                    st[nb] = __builtin_amdgcn_mfma_f32_16x16x32_bf16(
                        kf, qf[ks], st[nb], 0, 0, 0);
                }
            }
            __builtin_amdgcn_s_setprio(0);

            // fixed-shift softmax: p = exp2(s*smul - 20)
            const bool diag = (kt == qt);
#pragma unroll
            for (int nb = 0; nb < 4; ++nb) {
                bf16x4 pk;
#pragma unroll
                for (int r = 0; r < 4; ++r) {
                    float arg = fmaf(st[nb][r], smul, -20.f);
                    if (diag) {
                        const int keyg = kt * 64 + nb * 16 + lq * 4 + r;
                        if (keyg > qg) arg = -1e30f;
                    }
                    const float pv = exp2f(arg);
                    lrun += pv;
                    pk[r] = (bf16)pv;
                }
                *(bf16x4*)(Pp + prow * PAD + nb * 16 + lq * 4) = pk;
            }
            // no barrier: P rows are wave-private (and only this wave's own
            // next-iter commit touches them -> per-wave DS order suffices)

            // O += P @ V
            __builtin_amdgcn_s_setprio(1);
#pragma unroll
            for (int ks = 0; ks < 2; ++ks) {
                const bf16x8 pf =
                    *(const bf16x8*)(Pp + prow * PAD + ks * 32 + lq * 8);
#pragma unroll
                for (int ni = 0; ni < 4; ++ni) {
                    const bf16x8 vf = *(const bf16x8*)(Vs[buf] + (ni * 16 + lm) * PAD +
                                                       ks * 32 + lq * 8);
                    oacc[ni] = __builtin_amdgcn_mfma_f32_16x16x32_bf16(
                        pf, vf, oacc[ni], 0, 0, 0);
                }
            }
            __builtin_amdgcn_s_setprio(0);
            buf ^= 1;
            // no trailing barrier: next iter writes the other buffer
        }

        // epilogue (barrier-free): reduce l across lq partners, bcast via shfl
        lrun += __shfl_xor(lrun, 16);
        lrun += __shfl_xor(lrun, 32);
        float linv[4];
#pragma unroll
        for (int r = 0; r < 4; ++r) linv[r] = 1.0f / __shfl(lrun, lq * 4 + r);
#pragma unroll
        for (int ni = 0; ni < 4; ++ni) {
            const int col = h * 64 + ni * 16 + lm;
#pragma unroll
            for (int r = 0; r < 4; ++r) {
                const int t = q0 + w * 16 + lq * 4 + r;
                O[((size_t)(b * TT + t)) * CC + col] = (bf16)(oacc[ni][r] * linv[r]);
            }
        }
    }
}

// ---------------------------------------------------------------------------
extern "C" void kernel_launch(void* const* d_in, const int* in_sizes, int n_in,
                              void* d_out, int out_size, void* d_ws, size_t ws_size,
                              hipStream_t stream) {
    const float* x = (const float*)d_in[0];       // (8192, 1024) f32
    const float* w_qkv = (const float*)d_in[1];   // (1024, 3072) f32
    const float* w_out = (const float*)d_in[2];   // (1024, 1024) f32

    char* ws = (char*)d_ws;
    const size_t M1 = (size_t)1 << 20;
    bf16* Qh = (bf16*)(ws);                  // (B,H,T,64)   16 MiB
    bf16* Kh = (bf16*)(ws + 16 * M1);        // (B,H,T,64)   16 MiB
    bf16* Vt = (bf16*)(ws + 32 * M1);        // (B,H,64,T)   16 MiB
    bf16* Ob = (bf16*)(ws + 48 * M1);        // (8192,1024)  16 MiB
    bf16* wqkvT = (bf16*)(ws + 64 * M1);     // (3072,1024)   6 MiB
    bf16* woutT = (bf16*)(ws + 70 * M1);     // (1024,1024)   2 MiB
    bf16* xbf = (bf16*)(ws + 72 * M1);       // (8192,1024)  16 MiB

    prep<<<8192, 256, 0, stream>>>(x, w_qkv, w_out, xbf, wqkvT, woutT);
    gemm256<1><<<dim3(3072 / 256, 8192 / 256), 512, 0, stream>>>(
        xbf, wqkvT, Qh, Kh, Vt, 8192, 3072, 1024);
    attn_kernel<<<1024, 256, 0, stream>>>(Qh, Kh, Vt, Ob);
    gemm_bt<0><<<dim3(1024 / 128, 8192 / 128), 256, 0, stream>>>(
        Ob, woutT, (float*)d_out, nullptr, nullptr, 8192, 1024, 1024);
}